// Round 7
// baseline (171.568 us; speedup 1.0000x reference)
//
#include <hip/hip_runtime.h>
#include <hip/hip_bf16.h>
#include <stdint.h>

#define NB 2
#define NS 2048
#define ND 1024
#define NH 16
#define NDH 64
#define NT (NB*NS)   // 4096 tokens

using f32x4  = __attribute__((ext_vector_type(4))) float;
using bf16x8 = __attribute__((ext_vector_type(8))) short;
using uint2v = __attribute__((ext_vector_type(2))) unsigned int;

typedef __attribute__((address_space(1))) unsigned int as1_uint;
typedef __attribute__((address_space(3))) unsigned int as3_uint;

__device__ __forceinline__ void llds16(void* l, const void* g) {
    // async global->LDS, 16B per lane; LDS dest = wave-uniform base + lane*16
    __builtin_amdgcn_global_load_lds((as1_uint*)g, (as3_uint*)l, 16, 0, 0);
}

__device__ __forceinline__ f32x4 mfma16(bf16x8 a, bf16x8 b, f32x4 c) {
    return __builtin_amdgcn_mfma_f32_16x16x32_bf16(a, b, c, 0, 0, 0);
}

__device__ __forceinline__ unsigned short f2bf(float f) {
    union { __hip_bfloat16 h; unsigned short u; } cv;
    cv.h = __float2bfloat16(f);
    return cv.u;
}

// cross-lane xor-16 / xor-32 reduces on the VALU pipe (no LDS latency)
__device__ __forceinline__ float fmax_x16(float v) {
    uint2v r = __builtin_amdgcn_permlane16_swap(__float_as_uint(v), __float_as_uint(v), false, false);
    return fmaxf(__uint_as_float(r.x), __uint_as_float(r.y));
}
__device__ __forceinline__ float fmax_x32(float v) {
    uint2v r = __builtin_amdgcn_permlane32_swap(__float_as_uint(v), __float_as_uint(v), false, false);
    return fmaxf(__uint_as_float(r.x), __uint_as_float(r.y));
}
__device__ __forceinline__ float fadd_x16(float v) {
    uint2v r = __builtin_amdgcn_permlane16_swap(__float_as_uint(v), __float_as_uint(v), false, false);
    return __uint_as_float(r.x) + __uint_as_float(r.y);
}
__device__ __forceinline__ float fadd_x32(float v) {
    uint2v r = __builtin_amdgcn_permlane32_swap(__float_as_uint(v), __float_as_uint(v), false, false);
    return __uint_as_float(r.x) + __uint_as_float(r.y);
}

// ---------------- fused weight prep (one launch) ----------------
// bid <  768 : Wq/Wk/Wv (H,D,DH) -> WcatT rows n = mat*1024+h*64+e, cols k=d
//              (Wq pre-scaled by 0.125*log2e -> scores in log2 domain)
// 768..1023  : W1 (D,D) -> W1T[n][k] = W1[k][n]
// 1024..1279 : W2 (D,D) -> W2T[n][k] = W2[k][n]
__global__ void k_prep(const float* __restrict__ Wq, const float* __restrict__ Wk,
                       const float* __restrict__ Wv, const float* __restrict__ W1,
                       const float* __restrict__ W2, unsigned short* __restrict__ WcatT,
                       unsigned short* __restrict__ W1T, unsigned short* __restrict__ W2T) {
    __shared__ float tile[64][65];
    int tid = threadIdx.x;
    int bid = blockIdx.x;
    if (bid < 768) {
        const float SCALEQ = 0.125f * 1.44269504088896f;
        int kt = bid & 15; bid >>= 4;
        int h  = bid & 15; bid >>= 4;
        int mat = bid;
        const float* W = (mat == 0) ? Wq : (mat == 1) ? Wk : Wv;
#pragma unroll
        for (int i = 0; i < 16; ++i) {
            int idx = tid + i * 256;
            int r = idx >> 6, e = idx & 63;
            tile[r][e] = W[(size_t)h * ND * NDH + (size_t)(kt * 64 + r) * NDH + e];
        }
        __syncthreads();
#pragma unroll
        for (int i = 0; i < 16; ++i) {
            int idx = tid + i * 256;
            int e = idx >> 6, r = idx & 63;
            float v = tile[r][e];
            if (mat == 0) v *= SCALEQ;
            WcatT[(size_t)(mat * 1024 + h * 64 + e) * ND + kt * 64 + r] = f2bf(v);
        }
    } else {
        const float* W = (bid < 1024) ? W1 : W2;
        unsigned short* WT = (bid < 1024) ? W1T : W2T;
        int lb = (bid - 768) & 255;
        int ntile = lb & 15;
        int ktile = lb >> 4;
#pragma unroll
        for (int i = 0; i < 16; ++i) {
            int idx = tid + i * 256;
            int r = idx >> 6, c = idx & 63;
            tile[r][c] = W[(size_t)(ktile * 64 + r) * ND + ntile * 64 + c];
        }
        __syncthreads();
#pragma unroll
        for (int i = 0; i < 16; ++i) {
            int idx = tid + i * 256;
            int c = idx >> 6, r = idx & 63;
            WT[(size_t)(ntile * 64 + c) * ND + ktile * 64 + r] = f2bf(tile[r][c]);
        }
    }
}

// ---------------- layernorm (f32 in -> bf16 out) ----------------
__global__ void k_ln(const float* __restrict__ x, const float* __restrict__ sc,
                     const float* __restrict__ bi, unsigned short* __restrict__ out) {
    int row = blockIdx.x;
    int tid = threadIdx.x;
    const float* xr = x + (size_t)row * ND;
    float4 v = reinterpret_cast<const float4*>(xr)[tid];
    float sum = v.x + v.y + v.z + v.w;
    float sq  = v.x * v.x + v.y * v.y + v.z * v.z + v.w * v.w;
#pragma unroll
    for (int off = 1; off < 64; off <<= 1) {
        sum += __shfl_xor(sum, off);
        sq  += __shfl_xor(sq, off);
    }
    __shared__ float ssum[4], ssq[4];
    int wave = tid >> 6;
    if ((tid & 63) == 0) { ssum[wave] = sum; ssq[wave] = sq; }
    __syncthreads();
    sum = ssum[0] + ssum[1] + ssum[2] + ssum[3];
    sq  = ssq[0] + ssq[1] + ssq[2] + ssq[3];
    float mu  = sum * (1.0f / ND);
    float var = sq * (1.0f / ND) - mu * mu;
    float rstd = rsqrtf(var + 1e-5f);
    float4 s4 = reinterpret_cast<const float4*>(sc)[tid];
    float4 b4 = reinterpret_cast<const float4*>(bi)[tid];
    ushort4 o;
    o.x = f2bf((v.x - mu) * rstd * s4.x + b4.x);
    o.y = f2bf((v.y - mu) * rstd * s4.y + b4.y);
    o.z = f2bf((v.z - mu) * rstd * s4.z + b4.z);
    o.w = f2bf((v.w - mu) * rstd * s4.w + b4.w);
    reinterpret_cast<ushort4*>(out + (size_t)row * ND)[tid] = o;
}

// ---------------- GEMM: C(MxN) = A(MxK,bf16) * Bt(NxK,bf16)^T ----------------
// 128x128 tile, BK=64, 4 waves 2x2, XOR-swizzled LDS, global_load_lds staging.
// 2-phase double-buffer: prefetch kt+1 with counted vmcnt(8), raw s_barrier.
template<bool BIAS, bool RELU, bool RES>
__global__ __launch_bounds__(256)
void k_gemm(const unsigned short* __restrict__ A, const unsigned short* __restrict__ Bt,
            const float* __restrict__ bias, const float* __restrict__ res,
            void* __restrict__ Cv, int N, int K) {
    __shared__ __align__(16) unsigned short As[2][128 * 64];
    __shared__ __align__(16) unsigned short Bs[2][128 * 64];
    int tid = threadIdx.x;
    int lane = tid & 63, wave = tid >> 6;
    int wm = wave >> 1, wn = wave & 1;
    int l16 = lane & 15, lg = lane >> 4;
    int ntiles = N >> 7;
    int wg = (blockIdx.x & 7) * (gridDim.x >> 3) + (blockIdx.x >> 3);  // XCD swizzle
    int mt = wg / ntiles;
    int nt = wg % ntiles;

    const unsigned short* Abase = A  + (size_t)(mt * 128) * K;
    const unsigned short* Bbase = Bt + (size_t)(nt * 128) * K;

    f32x4 acc[4][4];
#pragma unroll
    for (int i = 0; i < 4; ++i)
#pragma unroll
        for (int j = 0; j < 4; ++j) acc[i][j] = (f32x4){0.f, 0.f, 0.f, 0.f};

    int srow = tid >> 3;
    int sch  = tid & 7;
    int KT = K >> 6;

    auto STAGE = [&](int kt, int bufi) {
#pragma unroll
        for (int i = 0; i < 4; ++i) {
            int row = srow + i * 32;
            int cs = sch ^ (row & 7);
            llds16((char*)As[bufi] + wave * 1024 + i * 4096,
                   Abase + (size_t)row * K + kt * 64 + cs * 8);
        }
#pragma unroll
        for (int i = 0; i < 4; ++i) {
            int row = srow + i * 32;
            int cs = sch ^ (row & 7);
            llds16((char*)Bs[bufi] + wave * 1024 + i * 4096,
                   Bbase + (size_t)row * K + kt * 64 + cs * 8);
        }
    };

    STAGE(0, 0);
    for (int kt = 0; kt < KT; ++kt) {
        int cb = kt & 1;
        if (kt + 1 < KT) {
            STAGE(kt + 1, cb ^ 1);
            asm volatile("s_waitcnt vmcnt(8)" ::: "memory");
        } else {
            asm volatile("s_waitcnt vmcnt(0)" ::: "memory");
        }
        __builtin_amdgcn_s_barrier();

        bf16x8 af[4][2], bfb[4][2];
#pragma unroll
        for (int mi = 0; mi < 4; ++mi)
#pragma unroll
            for (int kc = 0; kc < 2; ++kc) {
                int row = wm * 64 + mi * 16 + l16;
                int ch = (kc * 4 + lg) ^ (row & 7);
                af[mi][kc] = *reinterpret_cast<const bf16x8*>((const char*)As[cb] + row * 128 + ch * 16);
            }
#pragma unroll
        for (int ni = 0; ni < 4; ++ni)
#pragma unroll
            for (int kc = 0; kc < 2; ++kc) {
                int row = wn * 64 + ni * 16 + l16;
                int ch = (kc * 4 + lg) ^ (row & 7);
                bfb[ni][kc] = *reinterpret_cast<const bf16x8*>((const char*)Bs[cb] + row * 128 + ch * 16);
            }
#pragma unroll
        for (int mi = 0; mi < 4; ++mi)
#pragma unroll
            for (int ni = 0; ni < 4; ++ni) {
                acc[mi][ni] = mfma16(af[mi][0], bfb[ni][0], acc[mi][ni]);
                acc[mi][ni] = mfma16(af[mi][1], bfb[ni][1], acc[mi][ni]);
            }
        __builtin_amdgcn_s_barrier();
    }

#pragma unroll
    for (int mi = 0; mi < 4; ++mi)
#pragma unroll
        for (int ni = 0; ni < 4; ++ni) {
            int col = nt * 128 + wn * 64 + ni * 16 + l16;
            float bv = BIAS ? bias[col] : 0.f;
#pragma unroll
            for (int r = 0; r < 4; ++r) {
                int row = mt * 128 + wm * 64 + mi * 16 + lg * 4 + r;
                float v = acc[mi][ni][r] + bv;
                if (RELU) v = fmaxf(v, 0.f);
                size_t idx = (size_t)row * N + col;
                if (RES) ((float*)Cv)[idx] = v + res[idx];
                else ((unsigned short*)Cv)[idx] = f2bf(v);
            }
        }
}

// ---------------- fused causal flash attention + residual ----------------
// qk: (T x 2048) bf16 [Q|K per head]; VT: (1024 x 4096) bf16 = V^T per head.
// TWO q-tiles per block (q-tiles 2p, 2p+1 -> 128 q rows): K/V fragments are
// shared by both q-groups, halving staging+barriers per unit compute.
// Triple-buffered K/V, prefetch depth 2 (vmcnt(8) steady state).
// Grid 512 = exactly 2 blocks/CU; CU slot gets {p, 15-p} -> 34 staged tiles
// each (balanced, heavy-first). bh in low 5 bits -> per-XCD L2 pinning.
// Group A's final masked tile handled branchlessly (all-masked -> P=0).
__global__ __launch_bounds__(256)
void k_attn(const unsigned short* __restrict__ qk, const unsigned short* __restrict__ VT,
            const float* __restrict__ x, float* __restrict__ x2) {
    constexpr int ldq = 2 * ND;
    int bid = blockIdx.x;
    int c  = bid & 255;
    int g  = bid >> 8;
    int s  = c >> 5;
    int bh = c & 31;
    int p  = g ? s : 15 - s;
    int h = bh & 15, b = bh >> 4;
    int qbA = 2 * p, qbB = 2 * p + 1;
    int tid = threadIdx.x;
    int lane = tid & 63, wave = tid >> 6;
    int l16 = lane & 15, lg = lane >> 4;

    const unsigned short* Qp = qk + (size_t)b * NS * ldq + h * NDH;
    const unsigned short* Kp = Qp + ND;
    const unsigned short* Vp = VT + (size_t)(h * NDH) * NT + b * NS;  // [feat][token]

    __shared__ __align__(16) unsigned short Ks[3][64 * 64];   // [buf][key][feat] swizzled
    __shared__ __align__(16) unsigned short Vs[3][64 * 64];   // [buf][feat][key] swizzled
    __shared__ __align__(16) unsigned short Ps[4 * 2 * 1024]; // per-wave/group P swizzled

    int srow = tid >> 3;
    int sch  = tid & 7;
    int nt = qbB + 1;                      // >= 2 always
    int qwA = qbA * 64 + wave * 16;
    int qwB = qbB * 64 + wave * 16;

    bf16x8 qfA[2], qfB[2];
#pragma unroll
    for (int kc = 0; kc < 2; ++kc) {
        qfA[kc] = *reinterpret_cast<const bf16x8*>(Qp + (size_t)(qwA + l16) * ldq + kc * 32 + lg * 8);
        qfB[kc] = *reinterpret_cast<const bf16x8*>(Qp + (size_t)(qwB + l16) * ldq + kc * 32 + lg * 8);
    }

    f32x4 oA[4], oB[4];
#pragma unroll
    for (int i = 0; i < 4; ++i) { oA[i] = (f32x4){0.f,0.f,0.f,0.f}; oB[i] = (f32x4){0.f,0.f,0.f,0.f}; }
    float mA = -1.0e30f, lA = 0.0f, mB = -1.0e30f, lB = 0.0f;

    char* pbA = (char*)Ps + (wave * 2 + 0) * 2048 + l16 * 128;
    char* pbB = (char*)Ps + (wave * 2 + 1) * 2048 + l16 * 128;
    int psw = l16 & 7;

    auto STAGE = [&](int t, int bufi) {
#pragma unroll
        for (int i = 0; i < 2; ++i) {
            int row = srow + i * 32;
            int cs = sch ^ (row & 7);
            llds16((char*)Ks[bufi] + wave * 1024 + i * 4096,
                   Kp + (size_t)(t * 64 + row) * ldq + cs * 8);
        }
#pragma unroll
        for (int i = 0; i < 2; ++i) {
            int row = srow + i * 32;
            int cs = sch ^ (row & 7);
            llds16((char*)Vs[bufi] + wave * 1024 + i * 4096,
                   Vp + (size_t)row * NT + t * 64 + cs * 8);
        }
    };

    STAGE(0, 0);
    STAGE(1, 1);

    for (int t = 0; t < nt; ++t) {
        int buf = t % 3;
        if (t + 2 < nt) {
            STAGE(t + 2, (t + 2) % 3);
            asm volatile("s_waitcnt vmcnt(8)" ::: "memory");
        } else if (t + 1 < nt) {
            asm volatile("s_waitcnt vmcnt(4)" ::: "memory");
        } else {
            asm volatile("s_waitcnt vmcnt(0)" ::: "memory");
        }
        __builtin_amdgcn_s_barrier();

        const char* Kb = (const char*)Ks[buf];
        const char* Vb = (const char*)Vs[buf];

        // ---- ST = K @ Q^T for both q-groups (K fragment shared) ----
        f32x4 stA[4], stB[4];
#pragma unroll
        for (int mtt = 0; mtt < 4; ++mtt) { stA[mtt] = (f32x4){0.f,0.f,0.f,0.f}; stB[mtt] = (f32x4){0.f,0.f,0.f,0.f}; }
        __builtin_amdgcn_s_setprio(1);
#pragma unroll
        for (int kc = 0; kc < 2; ++kc)
#pragma unroll
            for (int mtt = 0; mtt < 4; ++mtt) {
                int row = mtt * 16 + l16;
                int ch = (kc * 4 + lg) ^ (row & 7);
                bf16x8 kf = *reinterpret_cast<const bf16x8*>(Kb + row * 128 + ch * 16);
                stA[mtt] = mfma16(kf, qfA[kc], stA[mtt]);
                stB[mtt] = mfma16(kf, qfB[kc], stB[mtt]);
            }
        __builtin_amdgcn_s_setprio(0);

        // ---- softmax group A (mask when t >= qbA; all-masked tile -> P=0) ----
        {
            float sv[4][4];
            float mx = -3.0e38f;
            if (t >= qbA) {
                int qg = qwA + l16;
#pragma unroll
                for (int mtt = 0; mtt < 4; ++mtt)
#pragma unroll
                    for (int r = 0; r < 4; ++r) {
                        int key = t * 64 + mtt * 16 + lg * 4 + r;
                        float s2 = (key <= qg) ? stA[mtt][r] : -1.0e30f;
                        sv[mtt][r] = s2;
                        mx = fmaxf(mx, s2);
                    }
            } else {
#pragma unroll
                for (int mtt = 0; mtt < 4; ++mtt)
#pragma unroll
                    for (int r = 0; r < 4; ++r) {
                        float s2 = stA[mtt][r];
                        sv[mtt][r] = s2;
                        mx = fmaxf(mx, s2);
                    }
            }
            mx = fmax_x16(mx);
            mx = fmax_x32(mx);
            if (__ballot(mx > mA + 8.0f)) {
                float mnew = fmaxf(mA, mx);
                float alpha = exp2f(mA - mnew);
                mA = mnew;
                lA *= alpha;
#pragma unroll
                for (int r = 0; r < 4; ++r) {
                    float ar = __shfl(alpha, (lane & 48) | (lg * 4 + r));
#pragma unroll
                    for (int ntt = 0; ntt < 4; ++ntt) oA[ntt][r] *= ar;
                }
            }
#pragma unroll
            for (int mtt = 0; mtt < 4; ++mtt) {
                float p0 = exp2f(sv[mtt][0] - mA);
                float p1 = exp2f(sv[mtt][1] - mA);
                float p2 = exp2f(sv[mtt][2] - mA);
                float p3 = exp2f(sv[mtt][3] - mA);
                lA += (p0 + p1) + (p2 + p3);
                int b0 = mtt * 32 + lg * 8;
                int sb = ((((b0 >> 4) ^ psw) << 4) | (b0 & 15));
                uint2 u;
                u.x = (unsigned)f2bf(p0) | ((unsigned)f2bf(p1) << 16);
                u.y = (unsigned)f2bf(p2) | ((unsigned)f2bf(p3) << 16);
                *reinterpret_cast<uint2*>(pbA + sb) = u;
            }
        }
        // ---- softmax group B (mask only when t == qbB) ----
        {
            float sv[4][4];
            float mx = -3.0e38f;
            if (t == qbB) {
                int qg = qwB + l16;
#pragma unroll
                for (int mtt = 0; mtt < 4; ++mtt)
#pragma unroll
                    for (int r = 0; r < 4; ++r) {
                        int key = t * 64 + mtt * 16 + lg * 4 + r;
                        float s2 = (key <= qg) ? stB[mtt][r] : -1.0e30f;
                        sv[mtt][r] = s2;
                        mx = fmaxf(mx, s2);
                    }
            } else {
#pragma unroll
                for (int mtt = 0; mtt < 4; ++mtt)
#pragma unroll
                    for (int r = 0; r < 4; ++r) {
                        float s2 = stB[mtt][r];
                        sv[mtt][r] = s2;
                        mx = fmaxf(mx, s2);
                    }
            }
            mx = fmax_x16(mx);
            mx = fmax_x32(mx);
            if (__ballot(mx > mB + 8.0f)) {
                float mnew = fmaxf(mB, mx);
                float alpha = exp2f(mB - mnew);
                mB = mnew;
                lB *= alpha;
#pragma unroll
                for (int r = 0; r < 4; ++r) {
                    float ar = __shfl(alpha, (lane & 48) | (lg * 4 + r));
#pragma unroll
                    for (int ntt = 0; ntt < 4; ++ntt) oB[ntt][r] *= ar;
                }
            }
#pragma unroll
            for (int mtt = 0; mtt < 4; ++mtt) {
                float p0 = exp2f(sv[mtt][0] - mB);
                float p1 = exp2f(sv[mtt][1] - mB);
                float p2 = exp2f(sv[mtt][2] - mB);
                float p3 = exp2f(sv[mtt][3] - mB);
                lB += (p0 + p1) + (p2 + p3);
                int b0 = mtt * 32 + lg * 8;
                int sb = ((((b0 >> 4) ^ psw) << 4) | (b0 & 15));
                uint2 u;
                u.x = (unsigned)f2bf(p0) | ((unsigned)f2bf(p1) << 16);
                u.y = (unsigned)f2bf(p2) | ((unsigned)f2bf(p3) << 16);
                *reinterpret_cast<uint2*>(pbB + sb) = u;
            }
        }

        asm volatile("s_waitcnt lgkmcnt(0)" ::: "memory");

        // ---- O += P @ V for both groups (V fragment shared) ----
        __builtin_amdgcn_s_setprio(1);
#pragma unroll
        for (int kc = 0; kc < 2; ++kc) {
            bf16x8 paA = *reinterpret_cast<const bf16x8*>(pbA + (((kc * 4 + lg) ^ psw) << 4));
            bf16x8 paB = *reinterpret_cast<const bf16x8*>(pbB + (((kc * 4 + lg) ^ psw) << 4));
#pragma unroll
            for (int ntt = 0; ntt < 4; ++ntt) {
                int vrow = ntt * 16 + l16;
                bf16x8 vb = *reinterpret_cast<const bf16x8*>(
                    Vb + vrow * 128 + ((((kc * 4 + lg) ^ (vrow & 7)) << 4)));
                oA[ntt] = mfma16(paA, vb, oA[ntt]);
                oB[ntt] = mfma16(paB, vb, oB[ntt]);
            }
        }
        __builtin_amdgcn_s_setprio(0);
        __builtin_amdgcn_s_barrier();
    }

    // epilogue: per group, reduce l across lane-halves, x2 = x + O/l
    float lrA = fadd_x32(fadd_x16(lA));
    float lrB = fadd_x32(fadd_x16(lB));
#pragma unroll
    for (int r = 0; r < 4; ++r) {
        int src = (lane & 48) | (lg * 4 + r);
        float livA = 1.0f / __shfl(lrA, src);
        float livB = 1.0f / __shfl(lrB, src);
        int tknA = b * NS + qwA + lg * 4 + r;
        int tknB = b * NS + qwB + lg * 4 + r;
        size_t baseA = (size_t)tknA * ND + h * NDH;
        size_t baseB = (size_t)tknB * ND + h * NDH;
#pragma unroll
        for (int ntt = 0; ntt < 4; ++ntt) {
            size_t iA = baseA + ntt * 16 + l16;
            size_t iB = baseB + ntt * 16 + l16;
            x2[iA] = x[iA] + oA[ntt][r] * livA;
            x2[iB] = x[iB] + oB[ntt][r] * livB;
        }
    }
}

// ---------------- launcher ----------------
extern "C" void kernel_launch(void* const* d_in, const int* in_sizes, int n_in,
                              void* d_out, int out_size, void* d_ws, size_t ws_size,
                              hipStream_t stream) {
    const float* x    = (const float*)d_in[0];
    // d_in[1] = padding_mask (all-true by construction; causal-only mask applied)
    const float* Wq   = (const float*)d_in[2];
    const float* Wk   = (const float*)d_in[3];
    const float* Wv   = (const float*)d_in[4];
    const float* ln1s = (const float*)d_in[5];
    const float* ln1b = (const float*)d_in[6];
    const float* ln2s = (const float*)d_in[7];
    const float* ln2b = (const float*)d_in[8];
    const float* W1   = (const float*)d_in[9];
    const float* b1   = (const float*)d_in[10];
    const float* W2   = (const float*)d_in[11];
    const float* b2   = (const float*)d_in[12];
    float* out = (float*)d_out;

    char* ws = (char*)d_ws;
    unsigned short* WcatT = (unsigned short*)(ws);              //  6,291,456 B
    unsigned short* W1T   = (unsigned short*)(ws + 6291456);    //  2,097,152 B
    unsigned short* W2T   = (unsigned short*)(ws + 8388608);    //  2,097,152 B
    unsigned short* hbuf  = (unsigned short*)(ws + 10485760);   //  8,388,608 B (h, then h2)
    unsigned short* qkbuf = (unsigned short*)(ws + 18874368);   // 16,777,216 B
    unsigned short* vtbuf = (unsigned short*)(ws + 35651584);   //  8,388,608 B (V^T)
    float*          x2    = (float*)(ws + 44040192);            // 16,777,216 B
    unsigned short* ubuf  = qkbuf;                               // overlay (dead after attn)

    k_prep<<<1280, 256, 0, stream>>>(Wq, Wk, Wv, W1, W2, WcatT, W1T, W2T);
    k_ln<<<NT, 256, 0, stream>>>(x, ln1s, ln1b, hbuf);
    // Q|K projection: (4096 x 2048) = hbuf @ WcatT[0:2048]^T
    k_gemm<false, false, false><<<(NT / 128) * (2048 / 128), 256, 0, stream>>>(
        hbuf, WcatT, nullptr, nullptr, qkbuf, 2048, 1024);
    // V^T projection: (1024 x 4096) = WcatT[2048:3072] @ hbuf^T  (free transpose)
    k_gemm<false, false, false><<<(1024 / 128) * (NT / 128), 256, 0, stream>>>(
        WcatT + (size_t)2048 * 1024, hbuf, nullptr, nullptr, vtbuf, NT, 1024);
    k_attn<<<512, 256, 0, stream>>>(qkbuf, vtbuf, x, x2);
    k_ln<<<NT, 256, 0, stream>>>(x2, ln2s, ln2b, hbuf);
    k_gemm<true, true, false><<<(NT / 128) * (1024 / 128), 256, 0, stream>>>(
        hbuf, W1T, b1, nullptr, ubuf, 1024, 1024);
    k_gemm<true, false, true><<<(NT / 128) * (1024 / 128), 256, 0, stream>>>(
        ubuf, W2T, b2, x2, out, 1024, 1024);
}

// Round 8
// 149.604 us; speedup vs baseline: 1.1468x; 1.1468x over previous
//
#include <hip/hip_runtime.h>
#include <hip/hip_bf16.h>
#include <stdint.h>

#define NB 2
#define NS 2048
#define ND 1024
#define NH 16
#define NDH 64
#define NT (NB*NS)   // 4096 tokens

using f32x4  = __attribute__((ext_vector_type(4))) float;
using bf16x8 = __attribute__((ext_vector_type(8))) short;
using uint2v = __attribute__((ext_vector_type(2))) unsigned int;

typedef __attribute__((address_space(1))) unsigned int as1_uint;
typedef __attribute__((address_space(3))) unsigned int as3_uint;

__device__ __forceinline__ void llds16(void* l, const void* g) {
    // async global->LDS, 16B per lane; LDS dest = wave-uniform base + lane*16
    __builtin_amdgcn_global_load_lds((as1_uint*)g, (as3_uint*)l, 16, 0, 0);
}

__device__ __forceinline__ f32x4 mfma16(bf16x8 a, bf16x8 b, f32x4 c) {
    return __builtin_amdgcn_mfma_f32_16x16x32_bf16(a, b, c, 0, 0, 0);
}

__device__ __forceinline__ unsigned short f2bf(float f) {
    union { __hip_bfloat16 h; unsigned short u; } cv;
    cv.h = __float2bfloat16(f);
    return cv.u;
}

// cross-lane xor-16 / xor-32 reduces on the VALU pipe (no LDS latency)
__device__ __forceinline__ float fmax_x16(float v) {
    uint2v r = __builtin_amdgcn_permlane16_swap(__float_as_uint(v), __float_as_uint(v), false, false);
    return fmaxf(__uint_as_float(r.x), __uint_as_float(r.y));
}
__device__ __forceinline__ float fmax_x32(float v) {
    uint2v r = __builtin_amdgcn_permlane32_swap(__float_as_uint(v), __float_as_uint(v), false, false);
    return fmaxf(__uint_as_float(r.x), __uint_as_float(r.y));
}
__device__ __forceinline__ float fadd_x16(float v) {
    uint2v r = __builtin_amdgcn_permlane16_swap(__float_as_uint(v), __float_as_uint(v), false, false);
    return __uint_as_float(r.x) + __uint_as_float(r.y);
}
__device__ __forceinline__ float fadd_x32(float v) {
    uint2v r = __builtin_amdgcn_permlane32_swap(__float_as_uint(v), __float_as_uint(v), false, false);
    return __uint_as_float(r.x) + __uint_as_float(r.y);
}

// ---------------- fused weight prep (one launch) ----------------
// bid <  768 : Wq/Wk/Wv (H,D,DH) -> WcatT rows n = mat*1024+h*64+e, cols k=d
//              (Wq pre-scaled by 0.125*log2e -> scores in log2 domain)
// 768..1023  : W1 (D,D) -> W1T[n][k] = W1[k][n]
// 1024..1279 : W2 (D,D) -> W2T[n][k] = W2[k][n]
__global__ void k_prep(const float* __restrict__ Wq, const float* __restrict__ Wk,
                       const float* __restrict__ Wv, const float* __restrict__ W1,
                       const float* __restrict__ W2, unsigned short* __restrict__ WcatT,
                       unsigned short* __restrict__ W1T, unsigned short* __restrict__ W2T) {
    __shared__ float tile[64][65];
    int tid = threadIdx.x;
    int bid = blockIdx.x;
    if (bid < 768) {
        const float SCALEQ = 0.125f * 1.44269504088896f;
        int kt = bid & 15; bid >>= 4;
        int h  = bid & 15; bid >>= 4;
        int mat = bid;
        const float* W = (mat == 0) ? Wq : (mat == 1) ? Wk : Wv;
#pragma unroll
        for (int i = 0; i < 16; ++i) {
            int idx = tid + i * 256;
            int r = idx >> 6, e = idx & 63;
            tile[r][e] = W[(size_t)h * ND * NDH + (size_t)(kt * 64 + r) * NDH + e];
        }
        __syncthreads();
#pragma unroll
        for (int i = 0; i < 16; ++i) {
            int idx = tid + i * 256;
            int e = idx >> 6, r = idx & 63;
            float v = tile[r][e];
            if (mat == 0) v *= SCALEQ;
            WcatT[(size_t)(mat * 1024 + h * 64 + e) * ND + kt * 64 + r] = f2bf(v);
        }
    } else {
        const float* W = (bid < 1024) ? W1 : W2;
        unsigned short* WT = (bid < 1024) ? W1T : W2T;
        int lb = (bid - 768) & 255;
        int ntile = lb & 15;
        int ktile = lb >> 4;
#pragma unroll
        for (int i = 0; i < 16; ++i) {
            int idx = tid + i * 256;
            int r = idx >> 6, c = idx & 63;
            tile[r][c] = W[(size_t)(ktile * 64 + r) * ND + ntile * 64 + c];
        }
        __syncthreads();
#pragma unroll
        for (int i = 0; i < 16; ++i) {
            int idx = tid + i * 256;
            int c = idx >> 6, r = idx & 63;
            WT[(size_t)(ntile * 64 + c) * ND + ktile * 64 + r] = f2bf(tile[r][c]);
        }
    }
}

// ---------------- layernorm (f32 in -> bf16 out) ----------------
__global__ void k_ln(const float* __restrict__ x, const float* __restrict__ sc,
                     const float* __restrict__ bi, unsigned short* __restrict__ out) {
    int row = blockIdx.x;
    int tid = threadIdx.x;
    const float* xr = x + (size_t)row * ND;
    float4 v = reinterpret_cast<const float4*>(xr)[tid];
    float sum = v.x + v.y + v.z + v.w;
    float sq  = v.x * v.x + v.y * v.y + v.z * v.z + v.w * v.w;
#pragma unroll
    for (int off = 1; off < 64; off <<= 1) {
        sum += __shfl_xor(sum, off);
        sq  += __shfl_xor(sq, off);
    }
    __shared__ float ssum[4], ssq[4];
    int wave = tid >> 6;
    if ((tid & 63) == 0) { ssum[wave] = sum; ssq[wave] = sq; }
    __syncthreads();
    sum = ssum[0] + ssum[1] + ssum[2] + ssum[3];
    sq  = ssq[0] + ssq[1] + ssq[2] + ssq[3];
    float mu  = sum * (1.0f / ND);
    float var = sq * (1.0f / ND) - mu * mu;
    float rstd = rsqrtf(var + 1e-5f);
    float4 s4 = reinterpret_cast<const float4*>(sc)[tid];
    float4 b4 = reinterpret_cast<const float4*>(bi)[tid];
    ushort4 o;
    o.x = f2bf((v.x - mu) * rstd * s4.x + b4.x);
    o.y = f2bf((v.y - mu) * rstd * s4.y + b4.y);
    o.z = f2bf((v.z - mu) * rstd * s4.z + b4.z);
    o.w = f2bf((v.w - mu) * rstd * s4.w + b4.w);
    reinterpret_cast<ushort4*>(out + (size_t)row * ND)[tid] = o;
}

// ---------------- GEMM: C(MxN) = A(MxK,bf16) * Bt(NxK,bf16)^T ----------------
// 64x128 tile, BK=64, 4 waves (2m x 2n -> 32x64 each), XOR-swizzled LDS,
// global_load_lds staging, 2-phase double-buffer with counted vmcnt(6) and raw
// s_barrier. LDS 48KB -> 3 blocks/CU; BM=64 doubles the grid for TLP (B-panel
// re-reads stay in L2/L3: weights <= 4MB).
template<bool BIAS, bool RELU, bool RES>
__global__ __launch_bounds__(256)
void k_gemm(const unsigned short* __restrict__ A, const unsigned short* __restrict__ Bt,
            const float* __restrict__ bias, const float* __restrict__ res,
            void* __restrict__ Cv, int N, int K) {
    __shared__ __align__(16) unsigned short As[2][64 * 64];
    __shared__ __align__(16) unsigned short Bs[2][128 * 64];
    int tid = threadIdx.x;
    int lane = tid & 63, wave = tid >> 6;
    int wm = wave >> 1, wn = wave & 1;
    int l16 = lane & 15, lg = lane >> 4;
    int ntiles = N >> 7;
    int wg = (blockIdx.x & 7) * (gridDim.x >> 3) + (blockIdx.x >> 3);  // XCD swizzle
    int mt = wg / ntiles;
    int nt = wg % ntiles;

    const unsigned short* Abase = A  + (size_t)(mt * 64) * K;
    const unsigned short* Bbase = Bt + (size_t)(nt * 128) * K;

    f32x4 acc[2][4];
#pragma unroll
    for (int i = 0; i < 2; ++i)
#pragma unroll
        for (int j = 0; j < 4; ++j) acc[i][j] = (f32x4){0.f, 0.f, 0.f, 0.f};

    int srow = tid >> 3;
    int sch  = tid & 7;
    int KT = K >> 6;

    auto STAGE = [&](int kt, int bufi) {
#pragma unroll
        for (int i = 0; i < 2; ++i) {
            int row = srow + i * 32;
            int cs = sch ^ (row & 7);
            llds16((char*)As[bufi] + wave * 1024 + i * 4096,
                   Abase + (size_t)row * K + kt * 64 + cs * 8);
        }
#pragma unroll
        for (int i = 0; i < 4; ++i) {
            int row = srow + i * 32;
            int cs = sch ^ (row & 7);
            llds16((char*)Bs[bufi] + wave * 1024 + i * 4096,
                   Bbase + (size_t)row * K + kt * 64 + cs * 8);
        }
    };

    STAGE(0, 0);
    for (int kt = 0; kt < KT; ++kt) {
        int cb = kt & 1;
        if (kt + 1 < KT) {
            STAGE(kt + 1, cb ^ 1);
            asm volatile("s_waitcnt vmcnt(6)" ::: "memory");
        } else {
            asm volatile("s_waitcnt vmcnt(0)" ::: "memory");
        }
        __builtin_amdgcn_s_barrier();

        bf16x8 af[2][2], bfb[4][2];
#pragma unroll
        for (int mi = 0; mi < 2; ++mi)
#pragma unroll
            for (int kc = 0; kc < 2; ++kc) {
                int row = wm * 32 + mi * 16 + l16;
                int ch = (kc * 4 + lg) ^ (row & 7);
                af[mi][kc] = *reinterpret_cast<const bf16x8*>((const char*)As[cb] + row * 128 + ch * 16);
            }
#pragma unroll
        for (int ni = 0; ni < 4; ++ni)
#pragma unroll
            for (int kc = 0; kc < 2; ++kc) {
                int row = wn * 64 + ni * 16 + l16;
                int ch = (kc * 4 + lg) ^ (row & 7);
                bfb[ni][kc] = *reinterpret_cast<const bf16x8*>((const char*)Bs[cb] + row * 128 + ch * 16);
            }
#pragma unroll
        for (int mi = 0; mi < 2; ++mi)
#pragma unroll
            for (int ni = 0; ni < 4; ++ni) {
                acc[mi][ni] = mfma16(af[mi][0], bfb[ni][0], acc[mi][ni]);
                acc[mi][ni] = mfma16(af[mi][1], bfb[ni][1], acc[mi][ni]);
            }
        __builtin_amdgcn_s_barrier();
    }

#pragma unroll
    for (int mi = 0; mi < 2; ++mi)
#pragma unroll
        for (int ni = 0; ni < 4; ++ni) {
            int col = nt * 128 + wn * 64 + ni * 16 + l16;
            float bv = BIAS ? bias[col] : 0.f;
#pragma unroll
            for (int r = 0; r < 4; ++r) {
                int row = mt * 64 + wm * 32 + mi * 16 + lg * 4 + r;
                float v = acc[mi][ni][r] + bv;
                if (RELU) v = fmaxf(v, 0.f);
                size_t idx = (size_t)row * N + col;
                if (RES) ((float*)Cv)[idx] = v + res[idx];
                else ((unsigned short*)Cv)[idx] = f2bf(v);
            }
        }
}

// ---------------- fused causal flash attention + residual ----------------
// (R6 structure, verbatim: best measured at 52.6us / 56 VGPR / 28% occ.)
// qk: (T x 2048) bf16 [Q|K per head]; VT: (1024 x 4096) bf16 = V^T per head.
// One q-tile (64 rows) per block, grid 1024 (4 blocks/CU co-resident).
// CU slot c gets bids {c,c+256,c+512,c+768} (round-robin dispatch), whose
// qb = {31-s,16+s,15-s,s} sum to 62 for every s -> uniform work per CU.
// K and V^T double-buffered in LDS via global_load_lds (counted vmcnt).
// Softmax: permlane max-reduce, per-lane l partial (reduced in epilogue).
// Scores in log2 domain (Wq pre-scaled by 0.125*log2e).
__global__ __launch_bounds__(256)
void k_attn(const unsigned short* __restrict__ qk, const unsigned short* __restrict__ VT,
            const float* __restrict__ x, float* __restrict__ x2) {
    constexpr int ldq = 2 * ND;
    int bid = blockIdx.x;
    int c  = bid & 255;
    int g  = bid >> 8;                 // 0..3 (resident-generation index)
    int s  = c >> 5;                   // 0..7
    int bh = c & 31;
    int qb = (g == 0) ? 31 - s : (g == 1) ? 16 + s : (g == 2) ? 15 - s : s;
    int h = bh & 15, b = bh >> 4;
    int tid = threadIdx.x;
    int lane = tid & 63, wave = tid >> 6;
    int l16 = lane & 15, lg = lane >> 4;

    const unsigned short* Qp = qk + (size_t)b * NS * ldq + h * NDH;
    const unsigned short* Kp = Qp + ND;
    const unsigned short* Vp = VT + (size_t)(h * NDH) * NT + b * NS;  // [feat][token], stride NT

    __shared__ __align__(16) unsigned short Ks[2][64 * 64];   // [buf][key][feat] swizzled
    __shared__ __align__(16) unsigned short Vs[2][64 * 64];   // [buf][feat][key] swizzled
    __shared__ __align__(16) unsigned short Ps[4][16 * 64];   // per-wave P [q][key] swizzled

    int srow = tid >> 3;         // 0..31
    int sch  = tid & 7;

    int nt = qb + 1;
    int qw = qb * 64 + wave * 16;     // wave's first q row (seq-local)

    // Q fragments (B-operand of K@Q^T), already scaled to log2 domain
    bf16x8 qf[2];
#pragma unroll
    for (int kc = 0; kc < 2; ++kc)
        qf[kc] = *reinterpret_cast<const bf16x8*>(Qp + (size_t)(qw + l16) * ldq + kc * 32 + lg * 8);

    f32x4 oacc[4];
#pragma unroll
    for (int i = 0; i < 4; ++i) oacc[i] = (f32x4){0.f, 0.f, 0.f, 0.f};
    float m_run = -1.0e30f, l_part = 0.0f;

    char* pbase = (char*)&Ps[wave][0] + l16 * 128;
    int psw = l16 & 7;                // row-swizzle key for this lane's P row

    // ---- prologue: stage K(0), V(0) ----
#pragma unroll
    for (int i = 0; i < 2; ++i) {
        int row = srow + i * 32;
        int cs = sch ^ (row & 7);
        llds16((char*)Ks[0] + wave * 1024 + i * 4096, Kp + (size_t)row * ldq + cs * 8);
    }
#pragma unroll
    for (int i = 0; i < 2; ++i) {
        int row = srow + i * 32;
        int cs = sch ^ (row & 7);
        llds16((char*)Vs[0] + wave * 1024 + i * 4096, Vp + (size_t)row * NT + cs * 8);
    }

    for (int t = 0; t < nt; ++t) {
        int cur = t & 1;
        const char* Kcur = (const char*)Ks[cur];
        const char* Vcur = (const char*)Vs[cur];

        // issue next K/V stage into the other buffer (4 llds16 stay in flight)
        if (t + 1 < nt) {
#pragma unroll
            for (int i = 0; i < 2; ++i) {
                int row = srow + i * 32;
                int cs = sch ^ (row & 7);
                llds16((char*)Ks[cur ^ 1] + wave * 1024 + i * 4096,
                       Kp + (size_t)((t + 1) * 64 + row) * ldq + cs * 8);
            }
#pragma unroll
            for (int i = 0; i < 2; ++i) {
                int row = srow + i * 32;
                int cs = sch ^ (row & 7);
                llds16((char*)Vs[cur ^ 1] + wave * 1024 + i * 4096,
                       Vp + (size_t)row * NT + (t + 1) * 64 + cs * 8);
            }
            asm volatile("s_waitcnt vmcnt(4)" ::: "memory");
        } else {
            asm volatile("s_waitcnt vmcnt(0)" ::: "memory");
        }
        __builtin_amdgcn_s_barrier();

        // ---- ST = K @ Q^T : lane holds ST[key = mtt*16+lg*4+r][q = l16] ----
        f32x4 st[4];
#pragma unroll
        for (int mtt = 0; mtt < 4; ++mtt) st[mtt] = (f32x4){0.f, 0.f, 0.f, 0.f};
        __builtin_amdgcn_s_setprio(1);
#pragma unroll
        for (int kc = 0; kc < 2; ++kc)
#pragma unroll
            for (int mtt = 0; mtt < 4; ++mtt) {
                int row = mtt * 16 + l16;
                int ch = (kc * 4 + lg) ^ (row & 7);
                bf16x8 kf = *reinterpret_cast<const bf16x8*>(Kcur + row * 128 + ch * 16);
                st[mtt] = mfma16(kf, qf[kc], st[mtt]);
            }
        __builtin_amdgcn_s_setprio(0);

        // online softmax per q-column (q = l16); mask only the diagonal tile
        float sv[4][4];
        float mx = -3.0e38f;
        if (t == qb) {
            int qg = qw + l16;
#pragma unroll
            for (int mtt = 0; mtt < 4; ++mtt)
#pragma unroll
                for (int r = 0; r < 4; ++r) {
                    int key = t * 64 + mtt * 16 + lg * 4 + r;
                    float s2 = (key <= qg) ? st[mtt][r] : -1.0e30f;
                    sv[mtt][r] = s2;
                    mx = fmaxf(mx, s2);
                }
        } else {
#pragma unroll
            for (int mtt = 0; mtt < 4; ++mtt)
#pragma unroll
                for (int r = 0; r < 4; ++r) {
                    float s2 = st[mtt][r];
                    sv[mtt][r] = s2;
                    mx = fmaxf(mx, s2);
                }
        }
        // cross-lane max over the 4 lanes of each q-column (VALU permlane, no LDS)
        mx = fmax_x16(mx);
        mx = fmax_x32(mx);

        // defer-max (THR = 8 in log2 units): rescale only when max grew a lot
        if (__ballot(mx > m_run + 8.0f)) {
            float mnew = fmaxf(m_run, mx);
            float alpha = exp2f(m_run - mnew);
            m_run = mnew;
            l_part *= alpha;
#pragma unroll
            for (int r = 0; r < 4; ++r) {
                float ar = __shfl(alpha, (lane & 48) | (lg * 4 + r));
#pragma unroll
                for (int ntt = 0; ntt < 4; ++ntt) oacc[ntt][r] *= ar;
            }
        }

#pragma unroll
        for (int mtt = 0; mtt < 4; ++mtt) {
            float p0 = exp2f(sv[mtt][0] - m_run);
            float p1 = exp2f(sv[mtt][1] - m_run);
            float p2 = exp2f(sv[mtt][2] - m_run);
            float p3 = exp2f(sv[mtt][3] - m_run);
            l_part += (p0 + p1) + (p2 + p3);
            // keys mtt*16+lg*4 .. +3 -> logical bytes b0..b0+7 (one b64 write)
            int b0 = mtt * 32 + lg * 8;
            int sb = ((((b0 >> 4) ^ psw) << 4) | (b0 & 15));
            uint2 u;
            u.x = (unsigned)f2bf(p0) | ((unsigned)f2bf(p1) << 16);
            u.y = (unsigned)f2bf(p2) | ((unsigned)f2bf(p3) << 16);
            *reinterpret_cast<uint2*>(pbase + sb) = u;
        }

        asm volatile("s_waitcnt lgkmcnt(0)" ::: "memory");

        // O += P @ V
        __builtin_amdgcn_s_setprio(1);
#pragma unroll
        for (int kc = 0; kc < 2; ++kc) {
            bf16x8 pa = *reinterpret_cast<const bf16x8*>(pbase + (((kc * 4 + lg) ^ psw) << 4));
#pragma unroll
            for (int ntt = 0; ntt < 4; ++ntt) {
                int vrow = ntt * 16 + l16;
                bf16x8 vb = *reinterpret_cast<const bf16x8*>(
                    Vcur + vrow * 128 + ((((kc * 4 + lg) ^ (vrow & 7)) << 4)));
                oacc[ntt] = mfma16(pa, vb, oacc[ntt]);
            }
        }
        __builtin_amdgcn_s_setprio(0);
        // protect Ks[cur]/Vs[cur] before next iteration's prefetch overwrites
        __builtin_amdgcn_s_barrier();
    }

    // epilogue: reduce l across the 4 lanes of each q-column, then x2 = x + O/l
    float l_run = fadd_x32(fadd_x16(l_part));
#pragma unroll
    for (int r = 0; r < 4; ++r) {
        float lv = __shfl(l_run, (lane & 48) | (lg * 4 + r));
        float linv = 1.0f / lv;
        int tkn = b * NS + qw + lg * 4 + r;
        size_t base = (size_t)tkn * ND + h * NDH;
#pragma unroll
        for (int ntt = 0; ntt < 4; ++ntt) {
            size_t idx = base + ntt * 16 + l16;
            x2[idx] = x[idx] + oacc[ntt][r] * linv;
        }
    }
}

// ---------------- launcher ----------------
extern "C" void kernel_launch(void* const* d_in, const int* in_sizes, int n_in,
                              void* d_out, int out_size, void* d_ws, size_t ws_size,
                              hipStream_t stream) {
    const float* x    = (const float*)d_in[0];
    // d_in[1] = padding_mask (all-true by construction; causal-only mask applied)
    const float* Wq   = (const float*)d_in[2];
    const float* Wk   = (const float*)d_in[3];
    const float* Wv   = (const float*)d_in[4];
    const float* ln1s = (const float*)d_in[5];
    const float* ln1b = (const float*)d_in[6];
    const float* ln2s = (const float*)d_in[7];
    const float* ln2b = (const float*)d_in[8];
    const float* W1   = (const float*)d_in[9];
    const float* b1   = (const float*)d_in[10];
    const float* W2   = (const float*)d_in[11];
    const float* b2   = (const float*)d_in[12];
    float* out = (float*)d_out;

    char* ws = (char*)d_ws;
    unsigned short* WcatT = (unsigned short*)(ws);              //  6,291,456 B
    unsigned short* W1T   = (unsigned short*)(ws + 6291456);    //  2,097,152 B
    unsigned short* W2T   = (unsigned short*)(ws + 8388608);    //  2,097,152 B
    unsigned short* hbuf  = (unsigned short*)(ws + 10485760);   //  8,388,608 B (h, then h2)
    unsigned short* qkbuf = (unsigned short*)(ws + 18874368);   // 16,777,216 B
    unsigned short* vtbuf = (unsigned short*)(ws + 35651584);   //  8,388,608 B (V^T)
    float*          x2    = (float*)(ws + 44040192);            // 16,777,216 B
    unsigned short* ubuf  = qkbuf;                               // overlay (dead after attn)

    k_prep<<<1280, 256, 0, stream>>>(Wq, Wk, Wv, W1, W2, WcatT, W1T, W2T);
    k_ln<<<NT, 256, 0, stream>>>(x, ln1s, ln1b, hbuf);
    // Q|K projection: (4096 x 2048) = hbuf @ WcatT[0:2048]^T
    k_gemm<false, false, false><<<(NT / 64) * (2048 / 128), 256, 0, stream>>>(
        hbuf, WcatT, nullptr, nullptr, qkbuf, 2048, 1024);
    // V^T projection: (1024 x 4096) = WcatT[2048:3072] @ hbuf^T  (free transpose)
    k_gemm<false, false, false><<<(1024 / 64) * (NT / 128), 256, 0, stream>>>(
        WcatT + (size_t)2048 * 1024, hbuf, nullptr, nullptr, vtbuf, NT, 1024);
    k_attn<<<NB * NH * 32, 256, 0, stream>>>(qkbuf, vtbuf, x, x2);
    k_ln<<<NT, 256, 0, stream>>>(x2, ln2s, ln2b, hbuf);
    k_gemm<true, true, false><<<(NT / 64) * (1024 / 128), 256, 0, stream>>>(
        hbuf, W1T, b1, nullptr, ubuf, 1024, 1024);
    k_gemm<true, false, true><<<(NT / 64) * (1024 / 128), 256, 0, stream>>>(
        ubuf, W2T, b2, x2, out, 1024, 1024);
}